// Round 1
// 3677.259 us; speedup vs baseline: 1.7451x; 1.7451x over previous
//
#include <hip/hip_runtime.h>

#define B_ 64
#define T_ 512
#define D_ 1024
#define H_ 1024

typedef _Float16 half8 __attribute__((ext_vector_type(8)));
typedef float floatx16 __attribute__((ext_vector_type(16)));

__device__ __forceinline__ float sigm(float x)   { return 1.f / (1.f + __expf(-x)); }
__device__ __forceinline__ float tanh_f(float x) { return 1.f - 2.f / (1.f + __expf(2.f * x)); }

// ---------------- prep: inputs fp32 -> f16 (8 elems / thread) ----------------
__global__ void k_prep_x(const float* __restrict__ x, _Float16* __restrict__ xf) {
  int i = blockIdx.x * blockDim.x + threadIdx.x;   // 0 .. 4194303
  const float4* p = (const float4*)x + (size_t)i * 2;
  float4 a = p[0], b = p[1];
  half8 v;
  v[0]=(_Float16)a.x; v[1]=(_Float16)a.y; v[2]=(_Float16)a.z; v[3]=(_Float16)a.w;
  v[4]=(_Float16)b.x; v[5]=(_Float16)b.y; v[6]=(_Float16)b.z; v[7]=(_Float16)b.w;
  ((half8*)xf)[i] = v;
}

// ---------------- prep: h_{-1} = init_h (f16), zero flags ----------------
__global__ void k_prep_misc(const float* __restrict__ init_h,
                            _Float16* __restrict__ hb1, int* __restrict__ flags) {
  int i = blockIdx.x * blockDim.x + threadIdx.x;   // grid 256x256 = 65536
  hb1[i] = (_Float16)init_h[i];
  if (i < 4096) flags[i] = 0;
}

// ---------------- persistent LSTM kernel ----------------
// 256 WGs (1/CU), 256 threads (4 waves). WG w: batch-half bh=w>>7, col-chunk jc=w&127
// (8 hidden cols -> 32 z-cols {gate*H + jc*8+jj}). LDS slab holds [Wi;Wh] slice,
// K=2048, in MFMA B-frag order: slab[kb*512 + lane*8 + j], kb=k/16.
//
// Cross-WG h exchange protocol (NO acquire fence / NO L2 invalidate anywhere):
//   writers: packed f16x2 relaxed AGENT atomic stores (write-through to LLC)
//            -> __syncthreads (drains vmcnt(0), i.e. LLC acks) -> flag relaxed store.
//   readers: each WAVE polls only ITS 32 producers' flags (lanes 0..31, relaxed
//            agent loads, bypass caches) -> then reads h via relaxed AGENT atomic
//            u64 loads, which are served at the LLC where the acked stores live.
//            Plain cached traffic (x stream, weights, out) stays warm in L2.
template <bool XF16>
__launch_bounds__(256, 1)
__global__ void k_lstm(const float* __restrict__ x32, const _Float16* __restrict__ xf,
                       const int* __restrict__ lengths, const float* __restrict__ init_c,
                       const float* __restrict__ Wi, const float* __restrict__ Wh,
                       const float* __restrict__ bias,
                       _Float16* __restrict__ hb0, _Float16* __restrict__ hb1,
                       int* __restrict__ flags,
                       float* __restrict__ out, float* __restrict__ finc,
                       float* __restrict__ finh)
{
  __shared__ _Float16 slab[65536];   // 128 KB: 128 kb-blocks x 512 f16
  __shared__ float red[4][32][40];   // 20 KB: wave partials, stride 40 = conflict-free

  const int w    = blockIdx.x;
  const int bh   = w >> 7;
  const int jc   = w & 127;
  const int t    = threadIdx.x;
  const int wave = t >> 6;
  const int lane = t & 63;
  const int m    = lane & 31;
  const int kh   = lane >> 5;

  // ---- one-time gather: weights -> LDS slab (f16, fragment order) ----
  {
    const int gate = m >> 3;
    const int col  = gate * H_ + jc * 8 + (m & 7);
    for (int kbb = 0; kbb < 32; ++kbb) {
      const int kb = kbb * 4 + wave;
      const int kc = kb * 16 + kh * 8;
      half8 v;
      #pragma unroll
      for (int j = 0; j < 8; ++j) {
        const int k = kc + j;
        const float f = (k < D_) ? Wi[(size_t)k * 4096 + col]
                                 : Wh[(size_t)(k - D_) * 4096 + col];
        v[j] = (_Float16)f;
      }
      *(half8*)&slab[kb * 512 + lane * 8] = v;
    }
  }

  // ---- per-thread gate-phase ids: one (batch, hidden-col) pair ----
  const int bl = t >> 3, jj = t & 7;
  const int bG = bh * 32 + bl;
  const int jG = jc * 8 + jj;
  float c = init_c[bG * H_ + jG];
  const int len = lengths[bG];
  const float bz0 = bias[0 * H_ + jG];
  const float bz1 = bias[1 * H_ + jG];
  const float bz2 = bias[2 * H_ + jG];
  const float bz3 = bias[3 * H_ + jG];

  const int bA = bh * 32 + m;                         // A-fragment row (batch)
  const _Float16* xbase   = XF16 ? (xf + (size_t)bA * T_ * D_ + kh * 8) : (const _Float16*)0;
  const float*    xbase32 = x32 + (size_t)bA * T_ * D_ + kh * 8;

  int* myflag_w = flags + (w << 4);                             // flags padded to 64 B
  int* pollflag = flags + ((bh * 128 + wave * 32 + m) << 4);    // wave's own 32 producers

  __syncthreads();

  // ---- x fragment registers, prefetched one step ahead (64 VGPRs) ----
  half8 xa[16];
  if (XF16) {
    const _Float16* xs = xbase;   // s = 0
    #pragma unroll
    for (int i = 0; i < 16; ++i)
      xa[i] = *(const half8*)(xs + (wave * 16 + i) * 16);
  }

  for (int s = 0; s < T_; ++s) {
    floatx16 C;
    #pragma unroll
    for (int r = 0; r < 16; ++r) C[r] = 0.f;

    // ---- x phase (independent of h; prefetched last step) ----
    if (XF16) {
      #pragma unroll
      for (int i = 0; i < 16; ++i) {
        const half8 bf = *(const half8*)&slab[(wave * 16 + i) * 512 + lane * 8];
        C = __builtin_amdgcn_mfma_f32_32x32x16_f16(xa[i], bf, C, 0, 0, 0);
      }
    } else {
      const float* xs = xbase32 + (size_t)s * D_;
      #pragma unroll
      for (int i = 0; i < 16; ++i) {
        const float4* p = (const float4*)(xs + (wave * 16 + i) * 16);
        float4 u0 = p[0], u1 = p[1];
        half8 v;
        v[0]=(_Float16)u0.x; v[1]=(_Float16)u0.y; v[2]=(_Float16)u0.z; v[3]=(_Float16)u0.w;
        v[4]=(_Float16)u1.x; v[5]=(_Float16)u1.y; v[6]=(_Float16)u1.z; v[7]=(_Float16)u1.w;
        const half8 bf = *(const half8*)&slab[(wave * 16 + i) * 512 + lane * 8];
        C = __builtin_amdgcn_mfma_f32_32x32x16_f16(v, bf, C, 0, 0, 0);
      }
    }

    // ---- wait for h_{s-1}: each wave polls only ITS 32 producers (lanes 0..31) ----
    // No __syncthreads here: waves proceed independently as soon as their own
    // K-range's producers have published. SIMT reconvergence = all 32 flags ready.
    if (lane < 32) {
      int spin = 0;
      while (__hip_atomic_load(pollflag, __ATOMIC_RELAXED, __HIP_MEMORY_SCOPE_AGENT) < s) {
        __builtin_amdgcn_s_sleep(1);
        if (++spin > (1 << 22)) break;   // safety valve against deadlock-hang
      }
    }

    // ---- h phase: agent-scope atomic u64 loads (LLC-served, no fence needed) ----
    const _Float16* hsrc = (s & 1) ? hb0 : hb1;   // h_{s-1} buffer
    unsigned long long* hq =
        (unsigned long long*)(hsrc + (size_t)bA * H_ + kh * 8);
    unsigned long long q[32];
    #pragma unroll
    for (int i = 0; i < 16; ++i) {
      unsigned long long* p = hq + (size_t)(wave * 16 + i) * 4;
      q[2 * i]     = __hip_atomic_load(p,     __ATOMIC_RELAXED, __HIP_MEMORY_SCOPE_AGENT);
      q[2 * i + 1] = __hip_atomic_load(p + 1, __ATOMIC_RELAXED, __HIP_MEMORY_SCOPE_AGENT);
    }
    #pragma unroll
    for (int i = 0; i < 16; ++i) {
      union { unsigned long long qq[2]; half8 v; } u;
      u.qq[0] = q[2 * i];
      u.qq[1] = q[2 * i + 1];
      const half8 bf = *(const half8*)&slab[(64 + wave * 16 + i) * 512 + lane * 8];
      C = __builtin_amdgcn_mfma_f32_32x32x16_f16(u.v, bf, C, 0, 0, 0);
    }

    // ---- reduce 4-wave partials (C/D layout: col=lane&31, row=(r&3)+8*(r>>2)+4*(lane>>5)) ----
    #pragma unroll
    for (int r = 0; r < 16; ++r) {
      const int row = (r & 3) + 8 * (r >> 2) + 4 * kh;
      red[wave][row][m] = C[r];
    }
    __syncthreads();

    const float z0 = red[0][bl][jj]      + red[1][bl][jj]      + red[2][bl][jj]      + red[3][bl][jj]      + bz0;
    const float z1 = red[0][bl][8 + jj]  + red[1][bl][8 + jj]  + red[2][bl][8 + jj]  + red[3][bl][8 + jj]  + bz1;
    const float z2 = red[0][bl][16 + jj] + red[1][bl][16 + jj] + red[2][bl][16 + jj] + red[3][bl][16 + jj] + bz2;
    const float z3 = red[0][bl][24 + jj] + red[1][bl][24 + jj] + red[2][bl][24 + jj] + red[3][bl][24 + jj] + bz3;

    const float ig = sigm(z0);
    const float fg = sigm(z1);
    const float gg = tanh_f(z2);
    const float og = sigm(z3);
    c = fg * c + ig * gg;
    const float hv = og * tanh_f(c);

    // ---- publish h_s FIRST (write-through to LLC, packed f16x2) ----
    {
      const float hv_other = __shfl_xor(hv, 1);   // partner lane jj^1 (same wave)
      if (!(t & 1)) {
        union { _Float16 h2[2]; unsigned u; } pk;
        pk.h2[0] = (_Float16)hv;
        pk.h2[1] = (_Float16)hv_other;
        _Float16* hdst = (s & 1) ? hb1 : hb0;
        __hip_atomic_store((unsigned*)(hdst + (size_t)bG * H_ + jG), pk.u,
                           __ATOMIC_RELAXED, __HIP_MEMORY_SCOPE_AGENT);
      }
    }

    // __syncthreads drains vmcnt(0) for every thread's h stores (LLC-acked)
    // before thread 0 publishes the flag. It also closes the red[] RAW/WAR window.
    __syncthreads();
    if (t == 0)
      __hip_atomic_store(myflag_w, s + 1, __ATOMIC_RELAXED, __HIP_MEMORY_SCOPE_AGENT);

    // ---- deferred outputs: off the flag critical path ----
    out[((size_t)bG * T_ + s) * H_ + jG] = hv;
    if (s == len - 1) { finc[bG * H_ + jG] = c; finh[bG * H_ + jG] = hv; }

    // ---- prefetch x for step s+1: lands during next poll phase ----
    if (XF16 && (s + 1 < T_)) {
      const _Float16* xs = xbase + (size_t)(s + 1) * D_;
      #pragma unroll
      for (int i = 0; i < 16; ++i)
        xa[i] = *(const half8*)(xs + (wave * 16 + i) * 16);
    }
  }
}

// ---------------- host ----------------
extern "C" void kernel_launch(void* const* d_in, const int* in_sizes, int n_in,
                              void* d_out, int out_size, void* d_ws, size_t ws_size,
                              hipStream_t stream) {
  const float* x32    = (const float*)d_in[0];
  const int*   lens   = (const int*)  d_in[1];
  const float* init_c = (const float*)d_in[2];
  const float* init_h = (const float*)d_in[3];
  const float* Wi     = (const float*)d_in[4];
  const float* Wh     = (const float*)d_in[5];
  const float* bias   = (const float*)d_in[6];

  float* out   = (float*)d_out;
  float* fin_c = out + (size_t)B_ * T_ * H_;
  float* fin_h = fin_c + (size_t)B_ * H_;

  char* ws = (char*)d_ws;
  int*       flags = (int*)ws;                         // 16 KB (256 flags, 64-B padded)
  _Float16*  hb0   = (_Float16*)(ws + 16384);          // 128 KB
  _Float16*  hb1   = hb0 + (size_t)B_ * H_;            // 128 KB
  _Float16*  xf16  = (_Float16*)(ws + (1u << 20));     // 64 MB

  const size_t need_big = (1u << 20) + sizeof(_Float16) * (size_t)B_ * T_ * D_;

  k_prep_misc<<<256, 256, 0, stream>>>(init_h, hb1, flags);
  if (ws_size >= need_big) {
    k_prep_x<<<16384, 256, 0, stream>>>(x32, xf16);
    k_lstm<true><<<256, 256, 0, stream>>>(x32, xf16, lens, init_c, Wi, Wh, bias,
                                          hb0, hb1, flags, out, fin_c, fin_h);
  } else {
    k_lstm<false><<<256, 256, 0, stream>>>(x32, xf16, lens, init_c, Wi, Wh, bias,
                                           hb0, hb1, flags, out, fin_c, fin_h);
  }
}

// Round 2
// 2470.786 us; speedup vs baseline: 2.5972x; 1.4883x over previous
//
#include <hip/hip_runtime.h>

#define B_ 64
#define T_ 512
#define D_ 1024
#define H_ 1024

typedef _Float16 half8 __attribute__((ext_vector_type(8)));
typedef float floatx16 __attribute__((ext_vector_type(16)));

__device__ __forceinline__ float sigm(float x)   { return 1.f / (1.f + __expf(-x)); }
__device__ __forceinline__ float tanh_f(float x) { return 1.f - 2.f / (1.f + __expf(2.f * x)); }

// ---------------- prep: inputs fp32 -> f16 (8 elems / thread) ----------------
__global__ void k_prep_x(const float* __restrict__ x, _Float16* __restrict__ xf) {
  int i = blockIdx.x * blockDim.x + threadIdx.x;   // 0 .. 4194303
  const float4* p = (const float4*)x + (size_t)i * 2;
  float4 a = p[0], b = p[1];
  half8 v;
  v[0]=(_Float16)a.x; v[1]=(_Float16)a.y; v[2]=(_Float16)a.z; v[3]=(_Float16)a.w;
  v[4]=(_Float16)b.x; v[5]=(_Float16)b.y; v[6]=(_Float16)b.z; v[7]=(_Float16)b.w;
  ((half8*)xf)[i] = v;
}

// ---------------- prep: h_{-1} = init_h (f16), zero flags ----------------
// (end-of-dispatch release flushes these stores to LLC before k_lstm starts)
__global__ void k_prep_misc(const float* __restrict__ init_h,
                            _Float16* __restrict__ hb1, int* __restrict__ flags) {
  int i = blockIdx.x * blockDim.x + threadIdx.x;   // grid 256x256 = 65536
  hb1[i] = (_Float16)init_h[i];
  if (i < 4096) flags[i] = 0;
}

// ---------------- persistent LSTM kernel ----------------
// 256 WGs (1/CU), 256 threads (4 waves). WG w: batch-half bh=w>>7, col-chunk jc=w&127
// (8 hidden cols -> 32 z-cols {gate*H + jc*8+jj}).
//
// LDS: slab      = Wh slice (K=1024), MFMA B-frag order, 64 KB.
//      hlds      = per-step staged h tile [32 batches][1024+4 pad] f16, 64.3 KB.
//                  wave W owns cols [W*256, W*256+256): stages and consumes them
//                  privately (no cross-wave barrier on hlds).
//      red       = 4-wave partial reduce, 20 KB.
// Wi slice lives in 64 permanent VGPRs (wia[16]) -> x-phase is pure-register MFMA.
//
// Cross-WG h exchange (NO fences / NO L2 invalidates):
//   writers: packed f16x2 relaxed AGENT atomic stores (write-through to LLC)
//            -> __syncthreads (drains vmcnt = LLC acks) -> flag relaxed store.
//   readers: per-wave poll of its own 32 producer flags (lanes 0..31), then
//            lane-CONTIGUOUS u64 agent atomic loads (512 B per wave-instr,
//            LLC-served) staged via LDS transpose into MFMA A-fragments.
template <bool XF16>
__launch_bounds__(256, 1)
__global__ void k_lstm(const float* __restrict__ x32, const _Float16* __restrict__ xf,
                       const int* __restrict__ lengths, const float* __restrict__ init_c,
                       const float* __restrict__ Wi, const float* __restrict__ Wh,
                       const float* __restrict__ bias,
                       _Float16* __restrict__ hb0, _Float16* __restrict__ hb1,
                       int* __restrict__ flags,
                       float* __restrict__ out, float* __restrict__ finc,
                       float* __restrict__ finh)
{
  __shared__ _Float16 slab[32768];       // 64 KB: 64 kb-blocks x 512 f16 (Wh only)
  __shared__ _Float16 hlds[32][1028];    // 64.3 KB: staged h, +4 halfs pad (2-way banks)
  __shared__ float red[4][32][40];       // 20 KB: wave partials, stride 40

  const int w    = blockIdx.x;
  const int bh   = w >> 7;
  const int jc   = w & 127;
  const int t    = threadIdx.x;
  const int wave = t >> 6;
  const int lane = t & 63;
  const int m    = lane & 31;
  const int kh   = lane >> 5;

  const int gate = m >> 3;
  const int col  = gate * H_ + jc * 8 + (m & 7);

  // ---- one-time: Wh slice -> LDS slab (f16, B-fragment order, kb = k/16) ----
  for (int kbb = 0; kbb < 16; ++kbb) {
    const int kb = kbb * 4 + wave;
    const int kc = kb * 16 + kh * 8;
    half8 v;
    #pragma unroll
    for (int j = 0; j < 8; ++j)
      v[j] = (_Float16)Wh[(size_t)(kc + j) * 4096 + col];
    *(half8*)&slab[kb * 512 + lane * 8] = v;
  }

  // ---- one-time: Wi slice -> 64 permanent VGPRs (B-fragment order) ----
  half8 wia[16];
  #pragma unroll
  for (int i = 0; i < 16; ++i) {
    const int kc = (wave * 16 + i) * 16 + kh * 8;
    half8 v;
    #pragma unroll
    for (int j = 0; j < 8; ++j)
      v[j] = (_Float16)Wi[(size_t)(kc + j) * 4096 + col];
    wia[i] = v;
  }

  // ---- per-thread gate-phase ids: one (batch, hidden-col) pair ----
  const int bl = t >> 3, jj = t & 7;
  const int bG = bh * 32 + bl;
  const int jG = jc * 8 + jj;
  float c = init_c[bG * H_ + jG];
  const int len = lengths[bG];
  const float bz0 = bias[0 * H_ + jG];
  const float bz1 = bias[1 * H_ + jG];
  const float bz2 = bias[2 * H_ + jG];
  const float bz3 = bias[3 * H_ + jG];

  const int bA = bh * 32 + m;                         // A-fragment row (batch)
  const _Float16* xbase   = XF16 ? (xf + (size_t)bA * T_ * D_ + kh * 8) : (const _Float16*)0;
  const float*    xbase32 = x32 + (size_t)bA * T_ * D_ + kh * 8;

  int* myflag_w = flags + (w << 4);                             // flags padded to 64 B
  int* pollflag = flags + ((bh * 128 + wave * 32 + m) << 4);    // wave's own 32 producers

  __syncthreads();

  // ---- x fragment registers, prefetched one step ahead (64 VGPRs) ----
  half8 xa[16];
  if (XF16) {
    const _Float16* xs = xbase;   // s = 0
    #pragma unroll
    for (int i = 0; i < 16; ++i)
      xa[i] = *(const half8*)(xs + (wave * 16 + i) * 16);
  }

  for (int s = 0; s < T_; ++s) {
    // ---- wait for h_{s-1}: each wave polls only ITS 32 producers ----
    if (lane < 32) {
      int spin = 0;
      while (__hip_atomic_load(pollflag, __ATOMIC_RELAXED, __HIP_MEMORY_SCOPE_AGENT) < s) {
        __builtin_amdgcn_s_sleep(1);
        if (++spin > (1 << 22)) break;   // safety valve against deadlock-hang
      }
    }

    // ---- issue coalesced h staging loads: wave's cols [wave*256, wave*256+256),
    //      32 batch rows. Lane-contiguous u64 -> 512 B per wave-instruction. ----
    const _Float16* hsrc = (s & 1) ? hb0 : hb1;   // h_{s-1} buffer
    const unsigned long long* hq =
        (const unsigned long long*)hsrc + (size_t)bh * 8192;   // bh*32*1024 halfs / 4
    unsigned long long q[32];
    #pragma unroll
    for (int r = 0; r < 32; ++r)
      q[r] = __hip_atomic_load(hq + r * 256 + wave * 64 + lane,
                               __ATOMIC_RELAXED, __HIP_MEMORY_SCOPE_AGENT);

    // ---- x phase (pure-register MFMA; overlaps the staging-load latency) ----
    floatx16 C;
    #pragma unroll
    for (int r = 0; r < 16; ++r) C[r] = 0.f;
    if (XF16) {
      #pragma unroll
      for (int i = 0; i < 16; ++i)
        C = __builtin_amdgcn_mfma_f32_32x32x16_f16(xa[i], wia[i], C, 0, 0, 0);
    } else {
      const float* xs = xbase32 + (size_t)s * D_;
      #pragma unroll
      for (int i = 0; i < 16; ++i) {
        const float4* p = (const float4*)(xs + (wave * 16 + i) * 16);
        float4 u0 = p[0], u1 = p[1];
        half8 v;
        v[0]=(_Float16)u0.x; v[1]=(_Float16)u0.y; v[2]=(_Float16)u0.z; v[3]=(_Float16)u0.w;
        v[4]=(_Float16)u1.x; v[5]=(_Float16)u1.y; v[6]=(_Float16)u1.z; v[7]=(_Float16)u1.w;
        C = __builtin_amdgcn_mfma_f32_32x32x16_f16(v, wia[i], C, 0, 0, 0);
      }
    }

    // ---- land staged h into LDS (2-way banks max), wave-private region ----
    #pragma unroll
    for (int r = 0; r < 32; ++r)
      *(unsigned long long*)&hlds[r][wave * 256 + lane * 4] = q[r];

    // ---- h phase: A-frags from LDS (row=m, k=col), B-frags from slab ----
    #pragma unroll
    for (int i = 0; i < 16; ++i) {
      const half8 av = *(const half8*)&hlds[m][wave * 256 + i * 16 + kh * 8];
      const half8 bf = *(const half8*)&slab[(wave * 16 + i) * 512 + lane * 8];
      C = __builtin_amdgcn_mfma_f32_32x32x16_f16(av, bf, C, 0, 0, 0);
    }

    // ---- reduce 4-wave partials (C/D layout: col=lane&31, row=(r&3)+8*(r>>2)+4*(lane>>5)) ----
    #pragma unroll
    for (int r = 0; r < 16; ++r) {
      const int row = (r & 3) + 8 * (r >> 2) + 4 * kh;
      red[wave][row][m] = C[r];
    }
    __syncthreads();

    const float z0 = red[0][bl][jj]      + red[1][bl][jj]      + red[2][bl][jj]      + red[3][bl][jj]      + bz0;
    const float z1 = red[0][bl][8 + jj]  + red[1][bl][8 + jj]  + red[2][bl][8 + jj]  + red[3][bl][8 + jj]  + bz1;
    const float z2 = red[0][bl][16 + jj] + red[1][bl][16 + jj] + red[2][bl][16 + jj] + red[3][bl][16 + jj] + bz2;
    const float z3 = red[0][bl][24 + jj] + red[1][bl][24 + jj] + red[2][bl][24 + jj] + red[3][bl][24 + jj] + bz3;

    const float ig = sigm(z0);
    const float fg = sigm(z1);
    const float gg = tanh_f(z2);
    const float og = sigm(z3);
    c = fg * c + ig * gg;
    const float hv = og * tanh_f(c);

    // ---- publish h_s FIRST (write-through to LLC, packed f16x2) ----
    {
      const float hv_other = __shfl_xor(hv, 1);   // partner lane jj^1 (same wave)
      if (!(t & 1)) {
        union { _Float16 h2[2]; unsigned u; } pk;
        pk.h2[0] = (_Float16)hv;
        pk.h2[1] = (_Float16)hv_other;
        _Float16* hdst = (s & 1) ? hb1 : hb0;
        __hip_atomic_store((unsigned*)(hdst + (size_t)bG * H_ + jG), pk.u,
                           __ATOMIC_RELAXED, __HIP_MEMORY_SCOPE_AGENT);
      }
    }

    // __syncthreads drains vmcnt(0) for every thread's h stores (LLC-acked)
    // before thread 0 publishes the flag. Also closes the red[] WAR window.
    __syncthreads();
    if (t == 0)
      __hip_atomic_store(myflag_w, s + 1, __ATOMIC_RELAXED, __HIP_MEMORY_SCOPE_AGENT);

    // ---- deferred outputs, NON-TEMPORAL: no 128-B write-allocate RMW fetch ----
    __builtin_nontemporal_store(hv, &out[((size_t)bG * T_ + s) * H_ + jG]);
    if (s == len - 1) {
      __builtin_nontemporal_store(c,  &finc[bG * H_ + jG]);
      __builtin_nontemporal_store(hv, &finh[bG * H_ + jG]);
    }

    // ---- prefetch x for step s+1: lands during next poll phase ----
    if (XF16 && (s + 1 < T_)) {
      const _Float16* xs = xbase + (size_t)(s + 1) * D_;
      #pragma unroll
      for (int i = 0; i < 16; ++i)
        xa[i] = *(const half8*)(xs + (wave * 16 + i) * 16);
    }
  }
}

// ---------------- host ----------------
extern "C" void kernel_launch(void* const* d_in, const int* in_sizes, int n_in,
                              void* d_out, int out_size, void* d_ws, size_t ws_size,
                              hipStream_t stream) {
  const float* x32    = (const float*)d_in[0];
  const int*   lens   = (const int*)  d_in[1];
  const float* init_c = (const float*)d_in[2];
  const float* init_h = (const float*)d_in[3];
  const float* Wi     = (const float*)d_in[4];
  const float* Wh     = (const float*)d_in[5];
  const float* bias   = (const float*)d_in[6];

  float* out   = (float*)d_out;
  float* fin_c = out + (size_t)B_ * T_ * H_;
  float* fin_h = fin_c + (size_t)B_ * H_;

  char* ws = (char*)d_ws;
  int*       flags = (int*)ws;                         // 16 KB (256 flags, 64-B padded)
  _Float16*  hb0   = (_Float16*)(ws + 16384);          // 128 KB
  _Float16*  hb1   = hb0 + (size_t)B_ * H_;            // 128 KB
  _Float16*  xf16  = (_Float16*)(ws + (1u << 20));     // 64 MB

  const size_t need_big = (1u << 20) + sizeof(_Float16) * (size_t)B_ * T_ * D_;

  k_prep_misc<<<256, 256, 0, stream>>>(init_h, hb1, flags);
  if (ws_size >= need_big) {
    k_prep_x<<<16384, 256, 0, stream>>>(x32, xf16);
    k_lstm<true><<<256, 256, 0, stream>>>(x32, xf16, lens, init_c, Wi, Wh, bias,
                                          hb0, hb1, flags, out, fin_c, fin_h);
  } else {
    k_lstm<false><<<256, 256, 0, stream>>>(x32, xf16, lens, init_c, Wi, Wh, bias,
                                           hb0, hb1, flags, out, fin_c, fin_h);
  }
}